// Round 3
// baseline (208.048 us; speedup 1.0000x reference)
//
#include <hip/hip_runtime.h>
#include <hip/hip_bf16.h>

// SAGAN self-attention, v3: MFMA everywhere, barrier-free flash main loop.
// B=8, C=64, N=4096, CQ=8.
// qkv: one 80x64 GEMM over pixels via mfma_f32_16x16x32_bf16.
// attn: per wave owns (q-tile, j-half). Phase 1: S^T = K.Q^T (C-frag col=q).
//       Phase 2 TRANSPOSED: O^T = V^T.P^T (B-frag n=q, same lane identity!)
//       -> P round-trips through wave-PRIVATE swizzled LDS, no __syncthreads
//       in the loop, denominator in registers. exp2 with Q pre-scaled by
//       1/ln2 at projection time; P packed to bf16 by RTZ v_perm (bias
//       cancels in softmax ratio).

#define B_   8
#define C_   64
#define N_   4096
#define CQ_  8
#define LOG2E 1.44269504088896340736f

typedef short bf16x8 __attribute__((ext_vector_type(8)));
typedef float f32x4  __attribute__((ext_vector_type(4)));
typedef unsigned int uint32;

#if __has_builtin(__builtin_amdgcn_exp2f)
#define EXP2(x) __builtin_amdgcn_exp2f(x)
#else
#define EXP2(x) __expf((x) * 0.69314718055994530942f)
#endif

__device__ __forceinline__ unsigned short f2bf_rn(float f) {
    union { __hip_bfloat16 h; unsigned short u; } cv;
    cv.h = __float2bfloat16(f);   // RNE
    return cv.u;
}
__device__ __forceinline__ uint32 pk_rn(float lo, float hi) {
    return (uint32)f2bf_rn(lo) | ((uint32)f2bf_rn(hi) << 16);
}
// RTZ pack: low word = bf16(lo), high word = bf16(hi). 1 v_perm_b32.
__device__ __forceinline__ uint32 pack_rtz(float lo, float hi) {
    return __builtin_amdgcn_perm(__float_as_uint(hi), __float_as_uint(lo), 0x07060302);
}

// ---------------------------------------------------------------------------
// QKV projection as MFMA GEMM: D[o][pix] = W[o][ch] . x[ch][pix] + b[o].
// Outputs: Qh [B][N][8] (pre-scaled by LOG2E), Kh [B][N][8], Vt [B][C][N].
// Grid: B * N/128 = 256 blocks, 256 threads (4 waves, 2 pixel-tiles each).
// ---------------------------------------------------------------------------
__global__ __launch_bounds__(256) void qkv_mfma_kernel(
    const float* __restrict__ x,
    const float* __restrict__ wq, const float* __restrict__ bq,
    const float* __restrict__ wk, const float* __restrict__ bk,
    const float* __restrict__ wv, const float* __restrict__ bv,
    unsigned short* __restrict__ Qh, unsigned short* __restrict__ Kh,
    unsigned short* __restrict__ Vt)
{
    __shared__ __align__(16) unsigned short Wl[80 * 72];  // rows 144B (pad: 2-way only)
    __shared__ __align__(16) uint32 xT[128 * 36];         // [pix][ch-pair], rows 144B

    const int t  = threadIdx.x;
    const int b  = blockIdx.x >> 5;          // 32 pixel-tiles per batch
    const int p0 = (blockIdx.x & 31) << 7;

    // stage weights bf16 (wq rows pre-scaled by LOG2E)
    for (int i = t; i < 5120; i += 256) {
        int o = i >> 6;
        float v;
        if (o < 8)       v = wq[i] * LOG2E;
        else if (o < 16) v = wk[i - 512];
        else             v = wv[i - 1024];
        Wl[o * 72 + (i & 63)] = f2bf_rn(v);
    }
    // stage x^T bf16: xT[pix][ch] (pairs packed; coalesced scalar global reads)
    for (int i = t; i < 4096; i += 256) {
        int p = i & 127, cp = i >> 7;
        float lo = x[((size_t)b * C_ + 2 * cp) * N_ + p0 + p];
        float hi = x[((size_t)b * C_ + 2 * cp + 1) * N_ + p0 + p];
        xT[p * 36 + cp] = pk_rn(lo, hi);
    }
    __syncthreads();

    const int w = t >> 6, lane = t & 63, l16 = lane & 15, qd = lane >> 4;

    // A-frags: W rows (A[m=o][k=ch], k = qd*8+j)
    bf16x8 af[5][2];
    #pragma unroll
    for (int mt = 0; mt < 5; ++mt)
        #pragma unroll
        for (int ks = 0; ks < 2; ++ks)
            af[mt][ks] = *(const bf16x8*)(Wl + (mt * 16 + l16) * 72 + ks * 32 + qd * 8);

    // biases per output row (row = mt*16 + qd*4 + r)
    float bias[5][4];
    #pragma unroll
    for (int mt = 0; mt < 5; ++mt)
        #pragma unroll
        for (int r = 0; r < 4; ++r) {
            int o = mt * 16 + qd * 4 + r;
            bias[mt][r] = (o < 8) ? bq[o] * LOG2E : (o < 16) ? bk[o - 8] : bv[o - 16];
        }

    #pragma unroll
    for (int n = 0; n < 2; ++n) {
        const int nt = w * 2 + n;
        bf16x8 bfr[2];   // B[k=ch][n=pix]: 16B from xT row pix
        #pragma unroll
        for (int ks = 0; ks < 2; ++ks)
            bfr[ks] = *(const bf16x8*)((const unsigned short*)xT + (nt * 16 + l16) * 72 + ks * 32 + qd * 8);
        const int pix = p0 + nt * 16 + l16;
        #pragma unroll
        for (int mt = 0; mt < 5; ++mt) {
            f32x4 acc = {bias[mt][0], bias[mt][1], bias[mt][2], bias[mt][3]};
            #pragma unroll
            for (int ks = 0; ks < 2; ++ks)
                acc = __builtin_amdgcn_mfma_f32_16x16x32_bf16(af[mt][ks], bfr[ks], acc, 0, 0, 0);
            // D: col=lane&15=pix, row=qd*4+r=o
            if (mt == 0) {
                uint2 u;
                u.x = pk_rn(acc[0], acc[1]);
                u.y = pk_rn(acc[2], acc[3]);
                if (qd < 2) *(uint2*)(Qh + ((size_t)b * N_ + pix) * CQ_ + qd * 4) = u;
                else        *(uint2*)(Kh + ((size_t)b * N_ + pix) * CQ_ + (qd - 2) * 4) = u;
            } else {
                #pragma unroll
                for (int r = 0; r < 4; ++r)
                    Vt[((size_t)b * C_ + mt * 16 + qd * 4 + r - 16) * N_ + pix] = f2bf_rn(acc[r]);
            }
        }
    }
}

// ---------------------------------------------------------------------------
// Flash attention, barrier-free main loop.
// Grid: B * N/64 = 512 blocks, 512 threads (8 waves).
// Wave w: q-tile qt = w&3, j-half jh = w>>2 (2048 j each, 32 iters of 64).
// ---------------------------------------------------------------------------
__global__ __launch_bounds__(512, 4) void attn_mfma2_kernel(
    const unsigned short* __restrict__ Qh,
    const unsigned short* __restrict__ Kh,
    const unsigned short* __restrict__ Vt,
    float* __restrict__ out)
{
    __shared__ __align__(16) char smem[32768];  // P: 2 bufs x 8 waves x 2KB; reused for epilogue

    const int t    = threadIdx.x;
    const int w    = t >> 6;
    const int lane = t & 63;
    const int l16  = lane & 15;
    const int qd   = lane >> 4;
    const int qt   = w & 3;
    const int jh   = w >> 2;
    const int b    = blockIdx.x >> 6;
    const int i0   = (blockIdx.x & 63) << 6;

    const bf16x8 z8 = {};
    const f32x4  zf = {};

    // Q frag (phase-1 B-operand, B[k=ch][n=q]); quads 1..3 zero (CQ=8 K-pad)
    bf16x8 qf = z8;
    if (qd == 0)
        qf = *(const bf16x8*)(Qh + ((size_t)b * N_ + i0 + qt * 16 + l16) * CQ_);

    // wave-private P buffer, XOR-swizzled (conflict-free b64 writes + b128 reads)
    const int swz   = (l16 & 7) << 2;        // dword-block xor
    const int pbase = w * 2048 + l16 * 128;  // row q=l16, 64 j = 128B
    int wa[4], ra[2];
    #pragma unroll
    for (int st = 0; st < 4; ++st) wa[st] = pbase + (((st * 8 + qd * 2) ^ swz) << 2);
    #pragma unroll
    for (int ks = 0; ks < 2; ++ks) ra[ks] = pbase + (((ks * 16 + qd * 4) ^ swz) << 2);

    const unsigned short* Kp = Kh + ((size_t)b * N_ + jh * 2048) * CQ_;
    const unsigned short* Vp = Vt + (size_t)b * C_ * N_ + jh * 2048;

    f32x4 acc[4] = {zf, zf, zf, zf};   // O^T quadrants: acc[ct], row c=ct*16+qd*4+r, col q=l16
    float dsum = 0.f;                  // per-lane partial denominator for q=l16

    // K-frag prefetch (A[m=j][k=ch], quads 1..3 zero)
    bf16x8 kf[4];
    #pragma unroll
    for (int st = 0; st < 4; ++st) {
        kf[st] = z8;
        if (qd == 0) kf[st] = *(const bf16x8*)(Kp + (st * 16 + l16) * CQ_);
    }

    #pragma unroll 2
    for (int it = 0; it < 32; ++it) {
        const int j0   = it * 64;
        const int bufo = (it & 1) << 14;

        // ---- phase 1: S^T[j][q] ----
        f32x4 s[4];
        #pragma unroll
        for (int st = 0; st < 4; ++st)
            s[st] = __builtin_amdgcn_mfma_f32_16x16x32_bf16(kf[st], qf, zf, 0, 0, 0);

        // prefetch next K tile (latency hidden behind this iteration)
        if (it < 31) {
            #pragma unroll
            for (int st = 0; st < 4; ++st) {
                bf16x8 nk = z8;
                if (qd == 0)
                    nk = *(const bf16x8*)(Kp + ((size_t)(j0 + 64 + st * 16 + l16)) * CQ_);
                kf[st] = nk;
            }
        }

        // V frags (phase-2 A-operand, A[m=c][k=j]) — direct global, L2-resident
        bf16x8 vf[4][2];
        #pragma unroll
        for (int ct = 0; ct < 4; ++ct)
            #pragma unroll
            for (int ks = 0; ks < 2; ++ks)
                vf[ct][ks] = *(const bf16x8*)(Vp + (size_t)(ct * 16 + l16) * N_ + j0 + ks * 32 + qd * 8);

        // ---- exp2 -> denominator + RTZ-pack P into wave-private LDS ----
        #pragma unroll
        for (int st = 0; st < 4; ++st) {
            float e0 = EXP2(s[st][0]);
            float e1 = EXP2(s[st][1]);
            float e2 = EXP2(s[st][2]);
            float e3 = EXP2(s[st][3]);
            dsum += (e0 + e1) + (e2 + e3);
            uint2 u;
            u.x = pack_rtz(e0, e1);
            u.y = pack_rtz(e2, e3);
            *(uint2*)(smem + bufo + wa[st]) = u;   // j = st*16+qd*4+{0..3}, row q=l16
        }

        // ---- phase 2: O^T += V^T . P^T ----
        #pragma unroll
        for (int ks = 0; ks < 2; ++ks) {
            bf16x8 pb = *(const bf16x8*)(smem + bufo + ra[ks]);   // B[k=j][n=q]
            #pragma unroll
            for (int ct = 0; ct < 4; ++ct)
                acc[ct] = __builtin_amdgcn_mfma_f32_16x16x32_bf16(vf[ct][ks], pb, acc[ct], 0, 0, 0);
        }
    }

    // ---- merge j-halves (only 2 barriers in the whole kernel) ----
    __syncthreads();
    float* Ef = (float*)smem;               // [4 waves][64 lanes][16]
    float* Dn = (float*)(smem + 16384);     // [4 waves][64]
    if (w >= 4) {
        float* dst = Ef + (size_t)((w - 4) * 64 + lane) * 16;
        #pragma unroll
        for (int ct = 0; ct < 4; ++ct) *(f32x4*)(dst + ct * 4) = acc[ct];
        Dn[(w - 4) * 64 + lane] = dsum;
    }
    __syncthreads();
    if (w < 4) {
        const float* src = Ef + (size_t)(w * 64 + lane) * 16;
        #pragma unroll
        for (int ct = 0; ct < 4; ++ct) {
            f32x4 p = *(const f32x4*)(src + ct * 4);
            acc[ct] += p;
        }
        dsum += Dn[w * 64 + lane];
        dsum += __shfl_xor(dsum, 16, 64);
        dsum += __shfl_xor(dsum, 32, 64);
        const float inv = 1.0f / dsum;
        #pragma unroll
        for (int ct = 0; ct < 4; ++ct)
            #pragma unroll
            for (int r = 0; r < 4; ++r)
                out[((size_t)b * C_ + ct * 16 + qd * 4 + r) * N_ + i0 + qt * 16 + l16] = acc[ct][r] * inv;
    }
}

// ---------------------------------------------------------------------------
// Fallback (workspace too small): round-1 fused fp32 flash kernel (verified).
// ---------------------------------------------------------------------------
__global__ __launch_bounds__(256) void attn_fused_fallback(
    const float* __restrict__ x,
    const float* __restrict__ wq, const float* __restrict__ bq,
    const float* __restrict__ wk, const float* __restrict__ bk,
    const float* __restrict__ wv, const float* __restrict__ bv,
    float* __restrict__ out)
{
    __shared__ float Qs[64][CQ_];
    __shared__ float Ks[CQ_][64];
    __shared__ float Vs[64][C_];
    __shared__ float Ws[64][64 + 1];
    __shared__ float Xs[C_ * 64];
    __shared__ float Wks[CQ_][C_];
    __shared__ float Wvs[C_][C_ + 1];

    const int t     = threadIdx.x;
    const int b     = blockIdx.x / (N_ / 64);
    const int i0    = (blockIdx.x % (N_ / 64)) * 64;
    const int jlane = t & 63;
    const int wgrp  = t >> 6;

    for (int l = t; l < CQ_ * C_; l += 256) Wks[l >> 6][l & 63] = wk[l];
    for (int l = t; l < C_ * C_;  l += 256) Wvs[l >> 6][l & 63] = wv[l];
    for (int l = t; l < C_ * 64;  l += 256)
        Xs[(l >> 6) * 64 + (l & 63)] = x[((size_t)b * C_ + (l >> 6)) * N_ + i0 + (l & 63)];
    __syncthreads();
    {
        int qi = jlane;
        #pragma unroll
        for (int r = 0; r < 2; ++r) {
            int cc = wgrp * 2 + r;
            float a = bq[cc];
            for (int c = 0; c < C_; ++c) a += wq[cc * C_ + c] * Xs[c * 64 + qi];
            Qs[qi][cc] = a;
        }
    }
    __syncthreads();

    const int qi2 = t >> 2;
    const int cb  = (t & 3) << 4;
    float accv[16];
    #pragma unroll
    for (int r = 0; r < 16; ++r) accv[r] = 0.f;
    float denom = 0.f;

    for (int j0 = 0; j0 < N_; j0 += 64) {
        for (int l = t; l < C_ * 64; l += 256)
            Xs[(l >> 6) * 64 + (l & 63)] = x[((size_t)b * C_ + (l >> 6)) * N_ + j0 + (l & 63)];
        __syncthreads();
        {
            int j = jlane;
            #pragma unroll
            for (int r = 0; r < 2; ++r) {
                int cc = wgrp * 2 + r;
                float a = bk[cc];
                for (int c = 0; c < C_; ++c) a += Wks[cc][c] * Xs[c * 64 + j];
                Ks[cc][j] = a;
            }
        }
        {
            int vc = jlane;
            #pragma unroll 2
            for (int r = 0; r < 16; ++r) {
                int j = wgrp * 16 + r;
                float a = bv[vc];
                for (int c = 0; c < C_; ++c) a += Wvs[vc][c] * Xs[c * 64 + j];
                Vs[j][vc] = a;
            }
        }
        __syncthreads();
        {
            float kreg[CQ_];
            #pragma unroll
            for (int cc = 0; cc < CQ_; ++cc) kreg[cc] = Ks[cc][jlane];
            #pragma unroll 4
            for (int r = 0; r < 16; ++r) {
                int qi = wgrp * 16 + r;
                float e = 0.f;
                #pragma unroll
                for (int cc = 0; cc < CQ_; ++cc) e += Qs[qi][cc] * kreg[cc];
                Ws[qi][jlane] = __expf(e);
            }
        }
        __syncthreads();
        #pragma unroll 4
        for (int j = 0; j < 64; ++j) {
            float wv2 = Ws[qi2][j];
            denom += wv2;
            const float4* vrow = (const float4*)(&Vs[j][cb]);
            float4 v0 = vrow[0], v1 = vrow[1], v2 = vrow[2], v3 = vrow[3];
            accv[0]  += wv2 * v0.x; accv[1]  += wv2 * v0.y; accv[2]  += wv2 * v0.z; accv[3]  += wv2 * v0.w;
            accv[4]  += wv2 * v1.x; accv[5]  += wv2 * v1.y; accv[6]  += wv2 * v1.z; accv[7]  += wv2 * v1.w;
            accv[8]  += wv2 * v2.x; accv[9]  += wv2 * v2.y; accv[10] += wv2 * v2.z; accv[11] += wv2 * v2.w;
            accv[12] += wv2 * v3.x; accv[13] += wv2 * v3.y; accv[14] += wv2 * v3.z; accv[15] += wv2 * v3.w;
        }
        __syncthreads();
    }

    const float inv = 1.0f / denom;
    #pragma unroll
    for (int r = 0; r < 16; ++r)
        out[((size_t)b * C_ + cb + r) * N_ + i0 + qi2] = accv[r] * inv;
}

// ---------------------------------------------------------------------------
extern "C" void kernel_launch(void* const* d_in, const int* in_sizes, int n_in,
                              void* d_out, int out_size, void* d_ws, size_t ws_size,
                              hipStream_t stream)
{
    const float* x  = (const float*)d_in[0];
    const float* wq = (const float*)d_in[1];
    const float* bq = (const float*)d_in[2];
    const float* wk = (const float*)d_in[3];
    const float* bk = (const float*)d_in[4];
    const float* wv = (const float*)d_in[5];
    const float* bv = (const float*)d_in[6];
    float* out = (float*)d_out;

    const size_t nQ = (size_t)B_ * N_ * CQ_;
    const size_t nV = (size_t)B_ * C_ * N_;
    const size_t needed = (2 * nQ + nV) * sizeof(unsigned short);   // 5 MB

    if (ws_size >= needed) {
        unsigned short* Qh = (unsigned short*)d_ws;
        unsigned short* Kh = Qh + nQ;
        unsigned short* Vt = Kh + nQ;
        qkv_mfma_kernel<<<B_ * (N_ / 128), 256, 0, stream>>>(x, wq, bq, wk, bk, wv, bv,
                                                             Qh, Kh, Vt);
        attn_mfma2_kernel<<<B_ * (N_ / 64), 512, 0, stream>>>(Qh, Kh, Vt, out);
    } else {
        attn_fused_fallback<<<B_ * (N_ / 64), 256, 0, stream>>>(x, wq, bq, wk, bk, wv, bv, out);
    }
}

// Round 4
// 127.467 us; speedup vs baseline: 1.6322x; 1.6322x over previous
//
#include <hip/hip_runtime.h>
#include <hip/hip_bf16.h>

// SAGAN self-attention v4. B=8, C=64, N=4096, CQ=8.
// Algebraic refactor: out = Wv.(X.P^T)/d + bv  -- V never materialized.
// prep: bf16 cast of x (Xb, same [B][C][N] layout) + Q/K projection (Q
//       pre-scaled by log2(e) so softmax uses exp2).
// attn: 4 waves, wave owns j-slice of 1024 (32 steps x 32 j) for ALL
//       4 q-tiles and ALL 64 channels:
//       p1: S^T = K.Q^T (16x16x32, K-pad, proven R2/R3 layout)
//       exp2 -> RTZ-pack -> wave-PRIVATE swizzled LDS (no barriers in loop)
//       p2: O' += X.P^T with X-frags in registers (loaded ONCE per block)
//       epilogue: cross-wave O' reduce, then fp32 Wv GEMM from LDS.

#define B_   8
#define C_   64
#define N_   4096
#define LOG2E 1.44269504088896340736f

typedef short bf16x8 __attribute__((ext_vector_type(8)));
typedef float f32x4  __attribute__((ext_vector_type(4)));
typedef unsigned int uint32;

#if __has_builtin(__builtin_amdgcn_exp2f)
#define EXP2(x) __builtin_amdgcn_exp2f(x)
#else
#define EXP2(x) __expf((x) * 0.69314718055994530942f)
#endif

__device__ __forceinline__ unsigned short f2bf_rn(float f) {
    union { __hip_bfloat16 h; unsigned short u; } cv;
    cv.h = __float2bfloat16(f);
    return cv.u;
}
__device__ __forceinline__ uint32 pk_rn(float lo, float hi) {
    return (uint32)f2bf_rn(lo) | ((uint32)f2bf_rn(hi) << 16);
}
// RTZ pack (1 v_perm): bias cancels in softmax ratio. Verified R2/R3.
__device__ __forceinline__ uint32 pack_rtz(float lo, float hi) {
    return __builtin_amdgcn_perm(__float_as_uint(hi), __float_as_uint(lo), 0x07060302);
}

// ---------------------------------------------------------------------------
// prep: Xb = bf16(x) (same layout), Qh/Kh = projections, [B][N][8] bf16.
// Grid: B * N/64 = 512 blocks, 256 threads.
// ---------------------------------------------------------------------------
__global__ __launch_bounds__(256) void prep_kernel(
    const float* __restrict__ x,
    const float* __restrict__ wq, const float* __restrict__ bq,
    const float* __restrict__ wk, const float* __restrict__ bk,
    unsigned short* __restrict__ Qh, unsigned short* __restrict__ Kh,
    unsigned short* __restrict__ Xb)
{
    __shared__ float Xs[C_][64];
    __shared__ float Wqk[16][C_];
    __shared__ float Bqk[16];

    const int t  = threadIdx.x;
    const int b  = blockIdx.x >> 6;
    const int p0 = (blockIdx.x & 63) << 6;

    for (int i = t; i < 1024; i += 256) {
        int o = i >> 6;
        Wqk[o][i & 63] = (o < 8) ? wq[i] * LOG2E : wk[i - 512];
    }
    if (t < 16) Bqk[t] = (t < 8) ? bq[t] * LOG2E : bk[t - 8];

    // stage x tile (fp32->LDS) + write bf16 cast (coalesced 4B stores)
    for (int i = t; i < 2048; i += 256) {
        int c = i >> 5, p2 = (i & 31) << 1;
        const float* xp = x + ((size_t)b * C_ + c) * N_ + p0 + p2;
        float2 v = *(const float2*)xp;
        Xs[c][p2] = v.x; Xs[c][p2 + 1] = v.y;
        *(uint32*)(Xb + ((size_t)b * C_ + c) * N_ + p0 + p2) = pk_rn(v.x, v.y);
    }
    __syncthreads();

    const int pix = t & 63, grp = t >> 6;   // grp wave-uniform
    float a[4];
    #pragma unroll
    for (int r = 0; r < 4; ++r) a[r] = Bqk[grp * 4 + r];
    for (int c = 0; c < C_; ++c) {
        float xv = Xs[c][pix];              // lanes consecutive: conflict-free
        #pragma unroll
        for (int r = 0; r < 4; ++r) a[r] += Wqk[grp * 4 + r][c] * xv;  // broadcast
    }
    #pragma unroll
    for (int r = 0; r < 4; ++r) {
        int o = grp * 4 + r;
        unsigned short hv = f2bf_rn(a[r]);
        if (o < 8) Qh[((size_t)b * N_ + p0 + pix) * 8 + o] = hv;
        else       Kh[((size_t)b * N_ + p0 + pix) * 8 + (o - 8)] = hv;
    }
}

// ---------------------------------------------------------------------------
// attn: grid B*N/64 = 512 blocks (b, 64-query tile), 256 threads (4 waves).
// Wave w: j in [w*1024, w*1024+1024), all 4 q-tiles, all 64 channels.
// ---------------------------------------------------------------------------
__global__ __launch_bounds__(256) void attn_mfma3_kernel(
    const unsigned short* __restrict__ Qh,
    const unsigned short* __restrict__ Kh,
    const unsigned short* __restrict__ Xb,
    const float* __restrict__ wv, const float* __restrict__ bv,
    float* __restrict__ out)
{
    // [0,16K): per-wave Ps (4KB each); epilogue: Wvs fp32 [64][64]
    // [16K,32K): RED r=0, then Or fp32 [64][64]
    // [32K,48K): RED r=1 ; [48K,64K): RED r=2 ; [64K,+1K): Dn [4][64]
    __shared__ __align__(16) char smem[66560];

    const int t    = threadIdx.x;
    const int w    = t >> 6;
    const int lane = t & 63;
    const int l16  = lane & 15;
    const int qd   = lane >> 4;
    const int b    = blockIdx.x >> 6;
    const int i0   = (blockIdx.x & 63) << 6;

    const bf16x8 z8 = {};
    const f32x4  zf = {};

    // Q frags (phase-1 B-operand, B[k=ch][n=q], quads 1-3 zero: K-pad)
    bf16x8 qf[4];
    #pragma unroll
    for (int qt = 0; qt < 4; ++qt) {
        qf[qt] = z8;
        if (qd == 0)
            qf[qt] = *(const bf16x8*)(Qh + ((size_t)b * N_ + i0 + qt * 16 + l16) * 8);
    }

    const unsigned short* Kp = Kh + ((size_t)b * N_ + w * 1024) * 8;
    const unsigned short* Xp = Xb + (size_t)b * C_ * N_ + w * 1024;

    f32x4 acc[4][4];   // [ct][qt]: O'(c=ct*16+qd*4+r, q=qt*16+l16)
    #pragma unroll
    for (int ct = 0; ct < 4; ++ct)
        #pragma unroll
        for (int qt = 0; qt < 4; ++qt) acc[ct][qt] = zf;
    float dsum[4] = {0.f, 0.f, 0.f, 0.f};

    // wave-private P addressing, XOR-swizzled (b64 writes & b128 reads uniform)
    const int swz   = (l16 & 3) << 2;
    const int wbase = w * 4096 + l16 * 64;
    int woff[2];
    #pragma unroll
    for (int jt = 0; jt < 2; ++jt) woff[jt] = ((jt * 8 + qd * 2) ^ swz) << 2;
    const int roff = ((qd * 4) ^ swz) << 2;

    // preload step 0
    bf16x8 kf[2][2], xf[2][4];
    #pragma unroll
    for (int jt = 0; jt < 2; ++jt) {
        kf[0][jt] = z8;
        if (qd == 0) kf[0][jt] = *(const bf16x8*)(Kp + (jt * 16 + l16) * 8);
    }
    #pragma unroll
    for (int ct = 0; ct < 4; ++ct)
        xf[0][ct] = *(const bf16x8*)(Xp + (size_t)(ct * 16 + l16) * N_ + qd * 8);

    #pragma unroll 2
    for (int s = 0; s < 32; ++s) {
        const int cur = s & 1, nxt = cur ^ 1;
        const int jb = s * 32;

        // phase 1: S^T[j][q] (rows j=jt*16+qd*4+r, col q=l16)
        f32x4 sf[2][4];
        #pragma unroll
        for (int jt = 0; jt < 2; ++jt)
            #pragma unroll
            for (int qt = 0; qt < 4; ++qt)
                sf[jt][qt] = __builtin_amdgcn_mfma_f32_16x16x32_bf16(kf[cur][jt], qf[qt], zf, 0, 0, 0);

        // prefetch next step's K and X frags (latency hidden behind exp/p2)
        if (s < 31) {
            #pragma unroll
            for (int jt = 0; jt < 2; ++jt) {
                bf16x8 nk = z8;
                if (qd == 0) nk = *(const bf16x8*)(Kp + (size_t)(jb + 32 + jt * 16 + l16) * 8);
                kf[nxt][jt] = nk;
            }
            #pragma unroll
            for (int ct = 0; ct < 4; ++ct)
                xf[nxt][ct] = *(const bf16x8*)(Xp + (size_t)(ct * 16 + l16) * N_ + jb + 32 + qd * 8);
        }

        // exp2 -> denom + pack to wave-private LDS
        #pragma unroll
        for (int jt = 0; jt < 2; ++jt)
            #pragma unroll
            for (int qt = 0; qt < 4; ++qt) {
                float e0 = EXP2(sf[jt][qt][0]);
                float e1 = EXP2(sf[jt][qt][1]);
                float e2 = EXP2(sf[jt][qt][2]);
                float e3 = EXP2(sf[jt][qt][3]);
                dsum[qt] += (e0 + e1) + (e2 + e3);
                uint2 u;
                u.x = pack_rtz(e0, e1);
                u.y = pack_rtz(e2, e3);
                *(uint2*)(smem + wbase + qt * 1024 + woff[jt]) = u;
            }

        // phase 2: O' += X . P^T  (A=X[m=c][k=j], B=P^T[k=j][n=q])
        #pragma unroll
        for (int qt = 0; qt < 4; ++qt) {
            bf16x8 pb = *(const bf16x8*)(smem + wbase + qt * 1024 + roff);
            #pragma unroll
            for (int ct = 0; ct < 4; ++ct)
                acc[ct][qt] = __builtin_amdgcn_mfma_f32_16x16x32_bf16(xf[cur][ct], pb, acc[ct][qt], 0, 0, 0);
        }
    }

    // ---- denominator partials ----
    #pragma unroll
    for (int qt = 0; qt < 4; ++qt) {
        float v = dsum[qt];
        v += __shfl_xor(v, 16, 64);
        v += __shfl_xor(v, 32, 64);
        if (qd == 0) *(float*)(smem + 65536 + (w * 64 + qt * 16 + l16) * 4) = v;
    }
    // ---- waves 1..3 dump O' partials ----
    if (w > 0) {
        char* rb = smem + 16384 + (w - 1) * 16384;
        #pragma unroll
        for (int ct = 0; ct < 4; ++ct)
            #pragma unroll
            for (int qt = 0; qt < 4; ++qt)
                *(f32x4*)(rb + (ct * 4 + qt) * 1024 + lane * 16) = acc[ct][qt];
    }
    __syncthreads();

    if (w == 0) {
        // reduce 3 partials, scatter O' to [c][q] fp32
        #pragma unroll
        for (int rr = 0; rr < 3; ++rr)
            #pragma unroll
            for (int ct = 0; ct < 4; ++ct)
                #pragma unroll
                for (int qt = 0; qt < 4; ++qt) {
                    f32x4 p = *(const f32x4*)(smem + 16384 + rr * 16384 + (ct * 4 + qt) * 1024 + lane * 16);
                    acc[ct][qt] += p;
                }
        float* Or = (float*)(smem + 16384);
        #pragma unroll
        for (int ct = 0; ct < 4; ++ct)
            #pragma unroll
            for (int qt = 0; qt < 4; ++qt)
                #pragma unroll
                for (int r = 0; r < 4; ++r)
                    Or[(ct * 16 + qd * 4 + r) * 64 + qt * 16 + l16] = acc[ct][qt][r];
    } else {
        // stage Wv fp32 into [0,16K) (Ps region is dead for all waves now)
        float* Wvs = (float*)smem;
        for (int i = t - 64; i < 4096; i += 192) Wvs[i] = wv[i];
    }
    __syncthreads();

    // ---- epilogue: out = Wv.O'/d + bv, fp32 ----
    const int q = t & 63, grp = t >> 6;
    const float* Wvs = (const float*)smem;
    const float* Or  = (const float*)(smem + 16384);
    const float* Dn  = (const float*)(smem + 65536);
    const float inv = 1.0f / (Dn[q] + Dn[64 + q] + Dn[128 + q] + Dn[192 + q]);
    float o[16];
    #pragma unroll
    for (int r = 0; r < 16; ++r) o[r] = 0.f;
    for (int k = 0; k < 64; ++k) {
        float ov = Or[k * 64 + q];                      // lanes consecutive q
        #pragma unroll
        for (int r = 0; r < 16; ++r)
            o[r] += Wvs[(grp * 16 + r) * 64 + k] * ov;  // broadcast
    }
    #pragma unroll
    for (int r = 0; r < 16; ++r)
        out[((size_t)b * C_ + grp * 16 + r) * N_ + i0 + q] = o[r] * inv + bv[grp * 16 + r];
}

// ---------------------------------------------------------------------------
// Fallback (workspace too small): round-1 fused fp32 flash kernel (verified).
// ---------------------------------------------------------------------------
__global__ __launch_bounds__(256) void attn_fused_fallback(
    const float* __restrict__ x,
    const float* __restrict__ wq, const float* __restrict__ bq,
    const float* __restrict__ wk, const float* __restrict__ bk,
    const float* __restrict__ wv, const float* __restrict__ bv,
    float* __restrict__ out)
{
    __shared__ float Qs[64][8];
    __shared__ float Ks[8][64];
    __shared__ float Vs[64][C_];
    __shared__ float Ws[64][64 + 1];
    __shared__ float Xs[C_ * 64];
    __shared__ float Wks[8][C_];
    __shared__ float Wvs[C_][C_ + 1];

    const int t     = threadIdx.x;
    const int b     = blockIdx.x / (N_ / 64);
    const int i0    = (blockIdx.x % (N_ / 64)) * 64;
    const int jlane = t & 63;
    const int wgrp  = t >> 6;

    for (int l = t; l < 8 * C_;  l += 256) Wks[l >> 6][l & 63] = wk[l];
    for (int l = t; l < C_ * C_; l += 256) Wvs[l >> 6][l & 63] = wv[l];
    for (int l = t; l < C_ * 64; l += 256)
        Xs[(l >> 6) * 64 + (l & 63)] = x[((size_t)b * C_ + (l >> 6)) * N_ + i0 + (l & 63)];
    __syncthreads();
    {
        int qi = jlane;
        #pragma unroll
        for (int r = 0; r < 2; ++r) {
            int cc = wgrp * 2 + r;
            float a = bq[cc];
            for (int c = 0; c < C_; ++c) a += wq[cc * C_ + c] * Xs[c * 64 + qi];
            Qs[qi][cc] = a;
        }
    }
    __syncthreads();

    const int qi2 = t >> 2;
    const int cb  = (t & 3) << 4;
    float accv[16];
    #pragma unroll
    for (int r = 0; r < 16; ++r) accv[r] = 0.f;
    float denom = 0.f;

    for (int j0 = 0; j0 < N_; j0 += 64) {
        for (int l = t; l < C_ * 64; l += 256)
            Xs[(l >> 6) * 64 + (l & 63)] = x[((size_t)b * C_ + (l >> 6)) * N_ + j0 + (l & 63)];
        __syncthreads();
        {
            int j = jlane;
            #pragma unroll
            for (int r = 0; r < 2; ++r) {
                int cc = wgrp * 2 + r;
                float a = bk[cc];
                for (int c = 0; c < C_; ++c) a += Wks[cc][c] * Xs[c * 64 + j];
                Ks[cc][j] = a;
            }
        }
        {
            int vc = jlane;
            #pragma unroll 2
            for (int r = 0; r < 16; ++r) {
                int j = wgrp * 16 + r;
                float a = bv[vc];
                for (int c = 0; c < C_; ++c) a += Wvs[vc][c] * Xs[c * 64 + j];
                Vs[j][vc] = a;
            }
        }
        __syncthreads();
        {
            float kreg[8];
            #pragma unroll
            for (int cc = 0; cc < 8; ++cc) kreg[cc] = Ks[cc][jlane];
            #pragma unroll 4
            for (int r = 0; r < 16; ++r) {
                int qi = wgrp * 16 + r;
                float e = 0.f;
                #pragma unroll
                for (int cc = 0; cc < 8; ++cc) e += Qs[qi][cc] * kreg[cc];
                Ws[qi][jlane] = __expf(e);
            }
        }
        __syncthreads();
        #pragma unroll 4
        for (int j = 0; j < 64; ++j) {
            float wv2 = Ws[qi2][j];
            denom += wv2;
            const float4* vrow = (const float4*)(&Vs[j][cb]);
            float4 v0 = vrow[0], v1 = vrow[1], v2 = vrow[2], v3 = vrow[3];
            accv[0]  += wv2 * v0.x; accv[1]  += wv2 * v0.y; accv[2]  += wv2 * v0.z; accv[3]  += wv2 * v0.w;
            accv[4]  += wv2 * v1.x; accv[5]  += wv2 * v1.y; accv[6]  += wv2 * v1.z; accv[7]  += wv2 * v1.w;
            accv[8]  += wv2 * v2.x; accv[9]  += wv2 * v2.y; accv[10] += wv2 * v2.z; accv[11] += wv2 * v2.w;
            accv[12] += wv2 * v3.x; accv[13] += wv2 * v3.y; accv[14] += wv2 * v3.z; accv[15] += wv2 * v3.w;
        }
        __syncthreads();
    }

    const float inv = 1.0f / denom;
    #pragma unroll
    for (int r = 0; r < 16; ++r)
        out[((size_t)b * C_ + cb + r) * N_ + i0 + qi2] = accv[r] * inv;
}

// ---------------------------------------------------------------------------
extern "C" void kernel_launch(void* const* d_in, const int* in_sizes, int n_in,
                              void* d_out, int out_size, void* d_ws, size_t ws_size,
                              hipStream_t stream)
{
    const float* x  = (const float*)d_in[0];
    const float* wq = (const float*)d_in[1];
    const float* bq = (const float*)d_in[2];
    const float* wk = (const float*)d_in[3];
    const float* bk = (const float*)d_in[4];
    const float* wv = (const float*)d_in[5];
    const float* bv = (const float*)d_in[6];
    float* out = (float*)d_out;

    const size_t nQ = (size_t)B_ * N_ * 8;        // 256K elems
    const size_t nX = (size_t)B_ * C_ * N_;       // 2M elems
    const size_t needed = (2 * nQ + nX) * sizeof(unsigned short);   // 5 MB

    if (ws_size >= needed) {
        unsigned short* Qh = (unsigned short*)d_ws;
        unsigned short* Kh = Qh + nQ;
        unsigned short* Xb = Kh + nQ;
        prep_kernel<<<B_ * (N_ / 64), 256, 0, stream>>>(x, wq, bq, wk, bk, Qh, Kh, Xb);
        attn_mfma3_kernel<<<B_ * (N_ / 64), 256, 0, stream>>>(Qh, Kh, Xb, wv, bv, out);
    } else {
        attn_fused_fallback<<<B_ * (N_ / 64), 256, 0, stream>>>(x, wq, bq, wk, bk, wv, bv, out);
    }
}